// Round 3
// baseline (4363.926 us; speedup 1.0000x reference)
//
#include <hip/hip_runtime.h>
#include <cstdint>
#include <cstddef>

// ---------------- types / helpers ----------------
typedef __bf16 bf16x8 __attribute__((ext_vector_type(8)));
typedef float f32x4 __attribute__((ext_vector_type(4)));

__device__ __forceinline__ unsigned short f2bf(float f) {
  unsigned u = __float_as_uint(f);
  u += 0x7fffu + ((u >> 16) & 1u);   // RNE
  return (unsigned short)(u >> 16);
}
__device__ __forceinline__ float bf2f(unsigned short s) {
  return __uint_as_float(((unsigned)s) << 16);
}

// async global->LDS, 16B per lane, linear dest (wave-uniform base + lane*16)
__device__ __forceinline__ void gld_lds16(const void* g, void* l) {
  __builtin_amdgcn_global_load_lds(
      (const __attribute__((address_space(1))) void*)g,
      (__attribute__((address_space(3))) void*)l, 16, 0, 0);
}

#define BARM() do { __builtin_amdgcn_s_barrier(); asm volatile("" ::: "memory"); } while (0)
#define VMCNT0() asm volatile("s_waitcnt vmcnt(0)" ::: "memory")
#define LGKM0()  do { asm volatile("s_waitcnt lgkmcnt(0)" ::: "memory"); \
                      __builtin_amdgcn_sched_barrier(0); } while (0)

// ---------------- transpose + convert W [K][N] f32 -> Wt [N][K] bf16 ----------------
__global__ void transpose_w(const float* __restrict__ w, unsigned short* __restrict__ wt,
                            int K, int N) {
  __shared__ float tile[32][33];
  int nt = N >> 5;
  int bx = blockIdx.x % nt;   // n tile
  int by = blockIdx.x / nt;   // k tile
  int tx = threadIdx.x & 31, ty = threadIdx.x >> 5;  // 32x8
#pragma unroll
  for (int r = 0; r < 32; r += 8)
    tile[ty + r][tx] = w[(size_t)(by * 32 + ty + r) * N + bx * 32 + tx];
  __syncthreads();
#pragma unroll
  for (int r = 0; r < 32; r += 8)
    wt[(size_t)(bx * 32 + ty + r) * K + by * 32 + tx] = f2bf(tile[tx][ty + r]);
}

// ---------------- x f32 -> bf16 (chunk, zero-pad rows >= nvalid) ----------------
__global__ void cvt_x(const float* __restrict__ x, unsigned short* __restrict__ xb,
                      int rows, int nvalid, int D) {
  size_t total = (size_t)rows * D / 8;
  for (size_t i = (size_t)blockIdx.x * blockDim.x + threadIdx.x; i < total;
       i += (size_t)gridDim.x * blockDim.x) {
    size_t e = i * 8;
    int row = (int)(e / (size_t)D);
    uint4 ov;
    if (row < nvalid) {
      const float4* s = (const float4*)(x + e);
      float4 v0 = s[0], v1 = s[1];
      ov.x = (unsigned)f2bf(v0.x) | ((unsigned)f2bf(v0.y) << 16);
      ov.y = (unsigned)f2bf(v0.z) | ((unsigned)f2bf(v0.w) << 16);
      ov.z = (unsigned)f2bf(v1.x) | ((unsigned)f2bf(v1.y) << 16);
      ov.w = (unsigned)f2bf(v1.z) | ((unsigned)f2bf(v1.w) << 16);
    } else {
      ov.x = ov.y = ov.z = ov.w = 0u;
    }
    *(uint4*)(xb + e) = ov;
  }
}

// ---------------- 256x256 GEMM, BK=32, 2 blocks/CU: C = relu(A @ Bt^T + bias) ----------------
// 512 threads = 8 waves (2M x 4N); per-wave output 128x64. LDS: 2 slots x
// {A,B} x [256][32] bf16 = 64 KiB -> 2 blocks/CU (cross-block LDS/MFMA overlap).
// Swizzle (T2): 64B rows, XOR element bits 3-4 with row bits 1-2, applied on
// both the pre-swizzled global source (linear LDS dest) and the ds_read addr.
// Per K-tile t (slot s=t&1):
//   ph0: read A0-3+B0-3 (8 ds_read_b128); stage A(t+1)+B(t+1) -> slot s^1
//        (4 gld_lds; their regions' last readers were certified by t-1's
//        post-MFMA barriers); BAR; lgkm0; 16 MFMA; BAR
//   ph1: read A4-7; BAR; lgkm0; 16 MFMA; vmcnt(0) (drains ~800-cyc-old t+1
//        loads, post-MFMA so latency is hidden); BAR  -> tile t+1 certified
__device__ __forceinline__ bf16x8 read_frag(const unsigned short* region, int row, int kel) {
  int ke = kel ^ (((row >> 1) & 3) << 3);
  return *(const bf16x8*)(region + row * 32 + ke);
}

__device__ __forceinline__ void stage_half(const unsigned short* gpanel, int K, int kofs,
                                           unsigned short* region, int tid) {
#pragma unroll
  for (int r = 0; r < 2; ++r) {
    int row = r * 128 + (tid >> 2);
    int ke = ((tid & 3) * 8) ^ (((row >> 1) & 3) << 3);  // inverse-swizzled source
    gld_lds16(gpanel + (size_t)row * K + kofs + ke, region + r * 4096 + tid * 8);
  }
}

#define MFMA16(MB, BV)                                                          \
  do {                                                                          \
    __builtin_amdgcn_s_setprio(1);                                              \
    _Pragma("unroll") for (int mm = 0; mm < 4; ++mm) {                          \
      _Pragma("unroll") for (int nn = 0; nn < 4; ++nn)                          \
        acc[(MB) + mm][nn] = __builtin_amdgcn_mfma_f32_16x16x32_bf16(           \
            av[mm], BV[nn], acc[(MB) + mm][nn], 0, 0, 0);                       \
    }                                                                           \
    __builtin_amdgcn_s_setprio(0);                                              \
  } while (0)

__global__ __launch_bounds__(512, 4) void gemm256(
    const unsigned short* __restrict__ A,   // [M][K] bf16
    const unsigned short* __restrict__ Bt,  // [N][K] bf16
    const float* __restrict__ bias,         // [N] f32
    unsigned short* __restrict__ C,         // [M][N] bf16
    int N, int K) {
  __shared__ alignas(16) unsigned short lds[2][2][256][32];   // 64 KiB
  const int tid = threadIdx.x;
  const int w = tid >> 6, l = tid & 63;
  const int wm = w >> 2, wn = w & 3;
  const int lc = l & 15, lk8 = (l >> 4) * 8;

  // T1: bijective XCD swizzle (m204); bn-fast so an XCD chunk reuses A panels.
  const int nbn = N >> 8;
  const int nwg = gridDim.x;
  const int q = nwg >> 3, rr = nwg & 7;
  const int xcd = blockIdx.x & 7, ib = blockIdx.x >> 3;
  const int bswz = (xcd < rr ? xcd * (q + 1) : rr * (q + 1) + (xcd - rr) * q) + ib;
  const int bm = bswz / nbn, bn = bswz - bm * nbn;

  const unsigned short* Ap = A + (size_t)bm * 256 * K;
  const unsigned short* Bp = Bt + (size_t)bn * 256 * K;
  const int T = K >> 5;

  f32x4 acc[8][4] = {};

  // prologue: tile0 -> slot0; certify before first reads
  stage_half(Ap, K, 0, &lds[0][0][0][0], tid);
  stage_half(Bp, K, 0, &lds[0][1][0][0], tid);
  VMCNT0();
  BARM();

  for (int t = 0; t < T; ++t) {
    const int s = t & 1;
    const unsigned short* As = &lds[s][0][0][0];
    const unsigned short* Bs = &lds[s][1][0][0];
    unsigned short* An = &lds[s ^ 1][0][0][0];
    unsigned short* Bn = &lds[s ^ 1][1][0][0];
    bf16x8 av[4], b[4];

    // ---- ph0 ----
#pragma unroll
    for (int mm = 0; mm < 4; ++mm) av[mm] = read_frag(As, wm * 128 + mm * 16 + lc, lk8);
#pragma unroll
    for (int nn = 0; nn < 4; ++nn) b[nn] = read_frag(Bs, wn * 64 + nn * 16 + lc, lk8);
    if (t + 1 < T) {
      stage_half(Ap, K, (t + 1) * 32, An, tid);
      stage_half(Bp, K, (t + 1) * 32, Bn, tid);
    }
    BARM();
    LGKM0();
    MFMA16(0, b);
    BARM();

    // ---- ph1 ----
#pragma unroll
    for (int mm = 0; mm < 4; ++mm) av[mm] = read_frag(As, wm * 128 + (4 + mm) * 16 + lc, lk8);
    BARM();
    LGKM0();
    MFMA16(4, b);
    VMCNT0();   // post-MFMA: drains tile-(t+1) loads issued one phase-pair ago
    BARM();     // all waves certified -> slot s^1 readable next iteration
  }

  // ---------------- epilogue: acc -> LDS (bank-XOR) -> coalesced dwordx4 stores ----------------
  unsigned short* eps = &lds[0][0][0][0];   // reuse as [128][256] bf16 per round
  float bv[4];
#pragma unroll
  for (int nn = 0; nn < 4; ++nn) bv[nn] = bias[bn * 256 + wn * 64 + nn * 16 + lc];

#pragma unroll
  for (int r = 0; r < 2; ++r) {
    if (wm == r) {
#pragma unroll
      for (int mm = 0; mm < 8; ++mm) {
#pragma unroll
        for (int nn = 0; nn < 4; ++nn) {
          int lcol = wn * 64 + nn * 16 + lc;
#pragma unroll
          for (int j = 0; j < 4; ++j) {
            int lrow = mm * 16 + (l >> 4) * 4 + j;
            float v = fmaxf(acc[mm][nn][j] + bv[nn], 0.0f);
            eps[lrow * 256 + (lcol ^ (((lrow >> 2) & 3) << 3))] = f2bf(v);
          }
        }
      }
    }
    BARM();
#pragma unroll
    for (int it = 0; it < 8; ++it) {
      int flat = it * 512 + tid;          // 4096 = 128 rows x 32 col-blocks
      int lrow = flat >> 5, cb = flat & 31;
      int ce = (cb * 8) ^ (((lrow >> 2) & 3) << 3);
      uint4 v = *(const uint4*)&eps[lrow * 256 + ce];
      *(uint4*)&C[(size_t)(bm * 256 + r * 128 + lrow) * N + bn * 256 + cb * 8] = v;
    }
    BARM();
  }
}

// ---------------- segment mean pool (split: S sub-blocks per graph + reduce) ----------------
__global__ void pool_partial(const unsigned short* __restrict__ h2, const int* __restrict__ batch,
                             float* __restrict__ part, int n, int D, int S) {
  int g = blockIdx.x / S, sub = blockIdx.x - g * S;
  int lo, hi;
  { int a = 0, b = n; while (a < b) { int m = (a + b) >> 1; if (batch[m] < g) a = m + 1; else b = m; } lo = a; }
  { int a = lo, b = n; while (a < b) { int m = (a + b) >> 1; if (batch[m] < g + 1) a = m + 1; else b = m; } hi = a; }
  int t = threadIdx.x;  // 256 threads, 2 cols each
  float sx = 0.f, sy = 0.f;
  for (int r = lo + sub; r < hi; r += S) {
    unsigned v = *(const unsigned*)(h2 + (size_t)r * D + t * 2);
    sx += bf2f((unsigned short)(v & 0xffffu));
    sy += bf2f((unsigned short)(v >> 16));
  }
  float* o = part + (size_t)blockIdx.x * D + t * 2;
  o[0] = sx;
  o[1] = sy;
}

__global__ void pool_reduce(const float* __restrict__ part, const int* __restrict__ batch,
                            float* __restrict__ out, int n, int D, int S, int G) {
  int idx = blockIdx.x * blockDim.x + threadIdx.x;
  if (idx >= G * D) return;
  int g = idx / D, d = idx - g * D;
  int lo, hi;
  { int a = 0, b = n; while (a < b) { int m = (a + b) >> 1; if (batch[m] < g) a = m + 1; else b = m; } lo = a; }
  { int a = lo, b = n; while (a < b) { int m = (a + b) >> 1; if (batch[m] < g + 1) a = m + 1; else b = m; } hi = a; }
  float sum = 0.f;
  for (int k = 0; k < S; ++k) sum += part[(size_t)(g * S + k) * D + d];
  out[idx] = sum / (float)(hi - lo);
}

// ---------------- launcher ----------------
static inline size_t align256(size_t x) { return (x + 255) & ~(size_t)255; }

extern "C" void kernel_launch(void* const* d_in, const int* in_sizes, int n_in,
                              void* d_out, int out_size, void* d_ws, size_t ws_size,
                              hipStream_t stream) {
  const float* x = (const float*)d_in[0];
  // d_in[1] = edge_index (unused by the math)
  const int* batch = (const int*)d_in[2];
  const float* W0 = (const float*)d_in[3];
  const float* b0 = (const float*)d_in[4];
  const float* W1 = (const float*)d_in[5];
  const float* b1 = (const float*)d_in[6];
  const float* W2 = (const float*)d_in[7];
  const float* b2 = (const float*)d_in[8];
  float* out = (float*)d_out;

  const int Nn = in_sizes[2];                 // 100000 nodes
  const int DIN = 512, DH = 1024, DOUT = 512;
  const int G = out_size / DOUT;              // 128
  const int S = 8;                            // pool sub-blocks per graph
  const int Mpad = ((Nn + 255) / 256) * 256;  // 100096

  // workspace layout
  uint8_t* p = (uint8_t*)d_ws;
  unsigned short* W0t = (unsigned short*)p; p += align256((size_t)DH * DIN * 2);
  unsigned short* W1t = (unsigned short*)p; p += align256((size_t)DH * DH * 2);
  unsigned short* W2t = (unsigned short*)p; p += align256((size_t)DOUT * DH * 2);
  unsigned short* h2  = (unsigned short*)p; p += align256((size_t)Mpad * DOUT * 2);
  float* part         = (float*)p;          p += align256((size_t)G * S * DOUT * 4);
  size_t used = (size_t)(p - (uint8_t*)d_ws);
  size_t avail = ws_size > used ? ws_size - used : 0;
  size_t per_row = (size_t)(DIN + DH + DH) * 2;       // xb + h0 + h1 bytes per row
  long long chl = (long long)(avail / per_row);
  chl = (chl / 256) * 256;
  int CH = (int)(chl < 256 ? 256 : chl);
  if (CH > Mpad) CH = Mpad;
  unsigned short* xb = (unsigned short*)p; p += align256((size_t)CH * DIN * 2);
  unsigned short* h0 = (unsigned short*)p; p += align256((size_t)CH * DH * 2);
  unsigned short* h1 = (unsigned short*)p; p += align256((size_t)CH * DH * 2);

  // 1) weights: transpose + convert to bf16 [N][K]
  transpose_w<<<dim3((DIN / 32) * (DH / 32)), 256, 0, stream>>>(W0, W0t, DIN, DH);
  transpose_w<<<dim3((DH / 32) * (DH / 32)), 256, 0, stream>>>(W1, W1t, DH, DH);
  transpose_w<<<dim3((DH / 32) * (DOUT / 32)), 256, 0, stream>>>(W2, W2t, DH, DOUT);

  // 2) chunked 3-layer MLP (single chunk when ws allows)
  for (int off = 0; off < Mpad; off += CH) {
    int rows = Mpad - off; if (rows > CH) rows = CH;
    int nvalid = Nn - off;
    size_t cvt_threads = (size_t)rows * DIN / 8;
    int cvt_blocks = (int)((cvt_threads + 255) / 256);
    if (cvt_blocks > 2048) cvt_blocks = 2048;
    cvt_x<<<dim3(cvt_blocks), 256, 0, stream>>>(x + (size_t)off * DIN, xb, rows, nvalid, DIN);

    gemm256<<<dim3((rows / 256) * (DH / 256)), 512, 0, stream>>>(xb, W0t, b0, h0, DH, DIN);
    gemm256<<<dim3((rows / 256) * (DH / 256)), 512, 0, stream>>>(h0, W1t, b1, h1, DH, DH);
    gemm256<<<dim3((rows / 256) * (DOUT / 256)), 512, 0, stream>>>(
        h1, W2t, b2, h2 + (size_t)off * DOUT, DOUT, DH);
  }

  // 3) per-graph mean pool
  pool_partial<<<dim3(G * S), 256, 0, stream>>>(h2, batch, part, Nn, DOUT, S);
  pool_reduce<<<dim3((G * DOUT + 255) / 256), 256, 0, stream>>>(part, batch, out, Nn, DOUT, S, G);
}

// Round 4
// 709.452 us; speedup vs baseline: 6.1511x; 6.1511x over previous
//
#include <hip/hip_runtime.h>
#include <cstdint>
#include <cstddef>

// ---------------- types / helpers ----------------
typedef __bf16 bf16x8 __attribute__((ext_vector_type(8)));
typedef float f32x4 __attribute__((ext_vector_type(4)));

__device__ __forceinline__ unsigned short f2bf(float f) {
  unsigned u = __float_as_uint(f);
  u += 0x7fffu + ((u >> 16) & 1u);   // RNE
  return (unsigned short)(u >> 16);
}
__device__ __forceinline__ float bf2f(unsigned short s) {
  return __uint_as_float(((unsigned)s) << 16);
}

// async global->LDS, 16B per lane, linear dest (wave-uniform base + lane*16)
__device__ __forceinline__ void gld_lds16(const void* g, void* l) {
  __builtin_amdgcn_global_load_lds(
      (const __attribute__((address_space(1))) void*)g,
      (__attribute__((address_space(3))) void*)l, 16, 0, 0);
}

#define BARM() do { __builtin_amdgcn_s_barrier(); asm volatile("" ::: "memory"); } while (0)
#define VMCNT(n) asm volatile("s_waitcnt vmcnt(" #n ")" ::: "memory")
#define LGKM0()  do { asm volatile("s_waitcnt lgkmcnt(0)" ::: "memory"); \
                      __builtin_amdgcn_sched_barrier(0); } while (0)

// ---------------- transpose + convert W [K][N] f32 -> Wt [N][K] bf16 ----------------
__global__ void transpose_w(const float* __restrict__ w, unsigned short* __restrict__ wt,
                            int K, int N) {
  __shared__ float tile[32][33];
  int nt = N >> 5;
  int bx = blockIdx.x % nt;   // n tile
  int by = blockIdx.x / nt;   // k tile
  int tx = threadIdx.x & 31, ty = threadIdx.x >> 5;  // 32x8
#pragma unroll
  for (int r = 0; r < 32; r += 8)
    tile[ty + r][tx] = w[(size_t)(by * 32 + ty + r) * N + bx * 32 + tx];
  __syncthreads();
#pragma unroll
  for (int r = 0; r < 32; r += 8)
    wt[(size_t)(bx * 32 + ty + r) * K + by * 32 + tx] = f2bf(tile[tx][ty + r]);
}

// ---------------- x f32 -> bf16 (chunk, zero-pad rows >= nvalid) ----------------
__global__ void cvt_x(const float* __restrict__ x, unsigned short* __restrict__ xb,
                      int rows, int nvalid, int D) {
  size_t total = (size_t)rows * D / 8;
  for (size_t i = (size_t)blockIdx.x * blockDim.x + threadIdx.x; i < total;
       i += (size_t)gridDim.x * blockDim.x) {
    size_t e = i * 8;
    int row = (int)(e / (size_t)D);
    uint4 ov;
    if (row < nvalid) {
      const float4* s = (const float4*)(x + e);
      float4 v0 = s[0], v1 = s[1];
      ov.x = (unsigned)f2bf(v0.x) | ((unsigned)f2bf(v0.y) << 16);
      ov.y = (unsigned)f2bf(v0.z) | ((unsigned)f2bf(v0.w) << 16);
      ov.z = (unsigned)f2bf(v1.x) | ((unsigned)f2bf(v1.y) << 16);
      ov.w = (unsigned)f2bf(v1.z) | ((unsigned)f2bf(v1.w) << 16);
    } else {
      ov.x = ov.y = ov.z = ov.w = 0u;
    }
    *(uint4*)(xb + e) = ov;
  }
}

// ---------------- 256x256 8-phase GEMM: C = relu(A @ Bt^T + bias) ----------------
// 512 threads = 8 waves (2M x 4N); per-wave output 128x64; BK=64 split into two
// k-half regions [256][32]. LDS: [slot][A/B][khalf][256][32] bf16 = 128 KiB.
// 1 block/CU, acc in AGPRs via launch_bounds(512,2) (round-3 lesson: (512,4)
// caps regs at 128/wave and spills the 128-reg accumulator to scratch).
// Schedule per K-tile group t (slot s=t&1), race-free by construction:
//   ph0: read A-k0(mf0-3)+B-k0; stage A-k1(t+1)->s^1; BAR; lgkm0; 16 MFMA; BAR
//   ph1: read A-k0(mf4-7);      stage B-k1(t+1)->s^1; BAR; lgkm0; 16 MFMA; BAR
//   ph2: read A-k1(mf0-3)+B-k1; stage A-k0(t+2)->s;   BAR; lgkm0; 16 MFMA; BAR
//   ph3: read A-k1(mf4-7);      stage B-k0(t+2)->s; vmcnt(4); BAR; lgkm0; 16 MFMA; BAR
// vmcnt(4) certifies tile t+1 landed while keeping tile t+2's k0 in flight
// (T4: never drain to 0 mid-loop).
__device__ __forceinline__ bf16x8 read_frag(const unsigned short* region, int row, int kel) {
  int ke = kel ^ (((row >> 1) & 3) << 3);
  return *(const bf16x8*)(region + row * 32 + ke);
}

__device__ __forceinline__ void stage_half(const unsigned short* gpanel, int K, int kofs,
                                           unsigned short* region, int tid) {
#pragma unroll
  for (int r = 0; r < 2; ++r) {
    int row = r * 128 + (tid >> 2);
    int ke = ((tid & 3) * 8) ^ (((row >> 1) & 3) << 3);  // inverse-swizzled source
    gld_lds16(gpanel + (size_t)row * K + kofs + ke, region + r * 4096 + tid * 8);
  }
}

#define MFMA16(MB, BV)                                                          \
  do {                                                                          \
    __builtin_amdgcn_s_setprio(1);                                              \
    _Pragma("unroll") for (int mm = 0; mm < 4; ++mm) {                          \
      _Pragma("unroll") for (int nn = 0; nn < 4; ++nn)                          \
        acc[(MB) + mm][nn] = __builtin_amdgcn_mfma_f32_16x16x32_bf16(           \
            av[mm], BV[nn], acc[(MB) + mm][nn], 0, 0, 0);                       \
    }                                                                           \
    __builtin_amdgcn_s_setprio(0);                                              \
  } while (0)

__global__ __launch_bounds__(512, 2) void gemm256(
    const unsigned short* __restrict__ A,   // [M][K] bf16
    const unsigned short* __restrict__ Bt,  // [N][K] bf16
    const float* __restrict__ bias,         // [N] f32
    unsigned short* __restrict__ C,         // [M][N] bf16
    int N, int K) {
  __shared__ alignas(16) unsigned short lds[2][2][2][256][32];   // 128 KiB
  const int tid = threadIdx.x;
  const int w = tid >> 6, l = tid & 63;
  const int wm = w >> 2, wn = w & 3;
  const int lc = l & 15, lk8 = (l >> 4) * 8;

  // T1: bijective XCD swizzle (m204); bn-fast so an XCD chunk reuses A panels.
  const int nbn = N >> 8;
  const int nwg = gridDim.x;
  const int q = nwg >> 3, rr = nwg & 7;
  const int xcd = blockIdx.x & 7, ib = blockIdx.x >> 3;
  const int bswz = (xcd < rr ? xcd * (q + 1) : rr * (q + 1) + (xcd - rr) * q) + ib;
  const int bm = bswz / nbn, bn = bswz - bm * nbn;

  const unsigned short* Ap = A + (size_t)bm * 256 * K;
  const unsigned short* Bp = Bt + (size_t)bn * 256 * K;
  const int T = K >> 6;

  f32x4 acc[8][4] = {};

  // prologue: tile0 (all 4 half-regions) + tile1 k0
  stage_half(Ap, K, 0, &lds[0][0][0][0][0], tid);
  stage_half(Bp, K, 0, &lds[0][1][0][0][0], tid);
  stage_half(Ap, K, 32, &lds[0][0][1][0][0], tid);
  stage_half(Bp, K, 32, &lds[0][1][1][0][0], tid);
  stage_half(Ap, K, 64, &lds[1][0][0][0][0], tid);
  stage_half(Bp, K, 64, &lds[1][1][0][0][0], tid);
  VMCNT(4);   // tile0 fully landed; tile1-k0's 4 loads stay in flight
  BARM();

  for (int t = 0; t < T; ++t) {
    const int s = t & 1;
    const unsigned short* Ak0 = &lds[s][0][0][0][0];
    const unsigned short* Ak1 = &lds[s][0][1][0][0];
    const unsigned short* Bk0 = &lds[s][1][0][0][0];
    const unsigned short* Bk1 = &lds[s][1][1][0][0];
    unsigned short* nAk1 = &lds[s ^ 1][0][1][0][0];
    unsigned short* nBk1 = &lds[s ^ 1][1][1][0][0];
    unsigned short* cAk0 = &lds[s][0][0][0][0];
    unsigned short* cBk0 = &lds[s][1][0][0][0];
    bf16x8 av[4], b0[4], b1[4];

    // ---- ph0 ----
#pragma unroll
    for (int mm = 0; mm < 4; ++mm) av[mm] = read_frag(Ak0, wm * 128 + mm * 16 + lc, lk8);
#pragma unroll
    for (int nn = 0; nn < 4; ++nn) b0[nn] = read_frag(Bk0, wn * 64 + nn * 16 + lc, lk8);
    if (t + 1 < T) stage_half(Ap, K, (t + 1) * 64 + 32, nAk1, tid);
    BARM();
    LGKM0();
    MFMA16(0, b0);
    BARM();

    // ---- ph1 ----
#pragma unroll
    for (int mm = 0; mm < 4; ++mm) av[mm] = read_frag(Ak0, wm * 128 + (4 + mm) * 16 + lc, lk8);
    if (t + 1 < T) stage_half(Bp, K, (t + 1) * 64 + 32, nBk1, tid);
    BARM();
    LGKM0();
    MFMA16(4, b0);
    BARM();

    // ---- ph2 ----
#pragma unroll
    for (int mm = 0; mm < 4; ++mm) av[mm] = read_frag(Ak1, wm * 128 + mm * 16 + lc, lk8);
#pragma unroll
    for (int nn = 0; nn < 4; ++nn) b1[nn] = read_frag(Bk1, wn * 64 + nn * 16 + lc, lk8);
    if (t + 2 < T) stage_half(Ap, K, (t + 2) * 64, cAk0, tid);
    BARM();
    LGKM0();
    MFMA16(0, b1);
    BARM();

    // ---- ph3 ----
#pragma unroll
    for (int mm = 0; mm < 4; ++mm) av[mm] = read_frag(Ak1, wm * 128 + (4 + mm) * 16 + lc, lk8);
    if (t + 2 < T) {
      stage_half(Bp, K, (t + 2) * 64, cBk0, tid);
      VMCNT(4);   // tile t+1 fully landed; tile t+2 k0 in flight
    } else {
      VMCNT(0);   // last boundary: drain (nothing left to overlap)
    }
    BARM();
    LGKM0();
    MFMA16(4, b1);
    BARM();
  }

  // ---- epilogue: acc -> LDS (row-XOR swizzle) -> coalesced dwordx4 stores ----
  // Slot 0 (64 KB) is free: last staged tile-T writes were guarded off, and the
  // final VMCNT(0)+BARM certified everything. eps = [128][256] bf16.
  unsigned short* eps = &lds[0][0][0][0][0];
  float bv[4];
#pragma unroll
  for (int nn = 0; nn < 4; ++nn) bv[nn] = bias[bn * 256 + wn * 64 + nn * 16 + lc];

#pragma unroll
  for (int r = 0; r < 2; ++r) {
    if (wm == r) {
#pragma unroll
      for (int mm = 0; mm < 8; ++mm) {
#pragma unroll
        for (int nn = 0; nn < 4; ++nn) {
          int lcol = wn * 64 + nn * 16 + lc;
#pragma unroll
          for (int j = 0; j < 4; ++j) {
            int lrow = mm * 16 + (l >> 4) * 4 + j;
            float v = fmaxf(acc[mm][nn][j] + bv[nn], 0.0f);
            eps[lrow * 256 + (lcol ^ (((lrow >> 2) & 3) << 4))] = f2bf(v);
          }
        }
      }
    }
    BARM();
#pragma unroll
    for (int it = 0; it < 8; ++it) {
      int flat = it * 512 + tid;          // 4096 = 128 rows x 32 col-granules
      int lrow = flat >> 5, cb = flat & 31;
      int ce = (cb * 8) ^ (((lrow >> 2) & 3) << 4);
      uint4 v = *(const uint4*)&eps[lrow * 256 + ce];
      *(uint4*)&C[(size_t)(bm * 256 + r * 128 + lrow) * N + bn * 256 + cb * 8] = v;
    }
    BARM();
  }
}

// ---------------- segment mean pool (split: S sub-blocks per graph + reduce) ----------------
__global__ void pool_partial(const unsigned short* __restrict__ h2, const int* __restrict__ batch,
                             float* __restrict__ part, int n, int D, int S) {
  int g = blockIdx.x / S, sub = blockIdx.x - g * S;
  int lo, hi;
  { int a = 0, b = n; while (a < b) { int m = (a + b) >> 1; if (batch[m] < g) a = m + 1; else b = m; } lo = a; }
  { int a = lo, b = n; while (a < b) { int m = (a + b) >> 1; if (batch[m] < g + 1) a = m + 1; else b = m; } hi = a; }
  int t = threadIdx.x;  // 256 threads, 2 cols each
  float sx = 0.f, sy = 0.f;
  for (int r = lo + sub; r < hi; r += S) {
    unsigned v = *(const unsigned*)(h2 + (size_t)r * D + t * 2);
    sx += bf2f((unsigned short)(v & 0xffffu));
    sy += bf2f((unsigned short)(v >> 16));
  }
  float* o = part + (size_t)blockIdx.x * D + t * 2;
  o[0] = sx;
  o[1] = sy;
}

__global__ void pool_reduce(const float* __restrict__ part, const int* __restrict__ batch,
                            float* __restrict__ out, int n, int D, int S, int G) {
  int idx = blockIdx.x * blockDim.x + threadIdx.x;
  if (idx >= G * D) return;
  int g = idx / D, d = idx - g * D;
  int lo, hi;
  { int a = 0, b = n; while (a < b) { int m = (a + b) >> 1; if (batch[m] < g) a = m + 1; else b = m; } lo = a; }
  { int a = lo, b = n; while (a < b) { int m = (a + b) >> 1; if (batch[m] < g + 1) a = m + 1; else b = m; } hi = a; }
  float sum = 0.f;
  for (int k = 0; k < S; ++k) sum += part[(size_t)(g * S + k) * D + d];
  out[idx] = sum / (float)(hi - lo);
}

// ---------------- launcher ----------------
static inline size_t align256(size_t x) { return (x + 255) & ~(size_t)255; }

extern "C" void kernel_launch(void* const* d_in, const int* in_sizes, int n_in,
                              void* d_out, int out_size, void* d_ws, size_t ws_size,
                              hipStream_t stream) {
  const float* x = (const float*)d_in[0];
  // d_in[1] = edge_index (unused by the math)
  const int* batch = (const int*)d_in[2];
  const float* W0 = (const float*)d_in[3];
  const float* b0 = (const float*)d_in[4];
  const float* W1 = (const float*)d_in[5];
  const float* b1 = (const float*)d_in[6];
  const float* W2 = (const float*)d_in[7];
  const float* b2 = (const float*)d_in[8];
  float* out = (float*)d_out;

  const int Nn = in_sizes[2];                 // 100000 nodes
  const int DIN = 512, DH = 1024, DOUT = 512;
  const int G = out_size / DOUT;              // 128
  const int S = 8;                            // pool sub-blocks per graph
  const int Mpad = ((Nn + 255) / 256) * 256;  // 100096

  // workspace layout
  uint8_t* p = (uint8_t*)d_ws;
  unsigned short* W0t = (unsigned short*)p; p += align256((size_t)DH * DIN * 2);
  unsigned short* W1t = (unsigned short*)p; p += align256((size_t)DH * DH * 2);
  unsigned short* W2t = (unsigned short*)p; p += align256((size_t)DOUT * DH * 2);
  unsigned short* h2  = (unsigned short*)p; p += align256((size_t)Mpad * DOUT * 2);
  float* part         = (float*)p;          p += align256((size_t)G * S * DOUT * 4);
  size_t used = (size_t)(p - (uint8_t*)d_ws);
  size_t avail = ws_size > used ? ws_size - used : 0;
  size_t per_row = (size_t)(DIN + DH + DH) * 2;       // xb + h0 + h1 bytes per row
  long long chl = (long long)(avail / per_row);
  chl = (chl / 256) * 256;
  int CH = (int)(chl < 256 ? 256 : chl);
  if (CH > Mpad) CH = Mpad;
  unsigned short* xb = (unsigned short*)p; p += align256((size_t)CH * DIN * 2);
  unsigned short* h0 = (unsigned short*)p; p += align256((size_t)CH * DH * 2);
  unsigned short* h1 = (unsigned short*)p; p += align256((size_t)CH * DH * 2);

  // 1) weights: transpose + convert to bf16 [N][K]
  transpose_w<<<dim3((DIN / 32) * (DH / 32)), 256, 0, stream>>>(W0, W0t, DIN, DH);
  transpose_w<<<dim3((DH / 32) * (DH / 32)), 256, 0, stream>>>(W1, W1t, DH, DH);
  transpose_w<<<dim3((DH / 32) * (DOUT / 32)), 256, 0, stream>>>(W2, W2t, DH, DOUT);

  // 2) chunked 3-layer MLP (single chunk when ws allows)
  for (int off = 0; off < Mpad; off += CH) {
    int rows = Mpad - off; if (rows > CH) rows = CH;
    int nvalid = Nn - off;
    size_t cvt_threads = (size_t)rows * DIN / 8;
    int cvt_blocks = (int)((cvt_threads + 255) / 256);
    if (cvt_blocks > 2048) cvt_blocks = 2048;
    cvt_x<<<dim3(cvt_blocks), 256, 0, stream>>>(x + (size_t)off * DIN, xb, rows, nvalid, DIN);

    gemm256<<<dim3((rows / 256) * (DH / 256)), 512, 0, stream>>>(xb, W0t, b0, h0, DH, DIN);
    gemm256<<<dim3((rows / 256) * (DH / 256)), 512, 0, stream>>>(h0, W1t, b1, h1, DH, DH);
    gemm256<<<dim3((rows / 256) * (DOUT / 256)), 512, 0, stream>>>(
        h1, W2t, b2, h2 + (size_t)off * DOUT, DOUT, DH);
  }

  // 3) per-graph mean pool
  pool_partial<<<dim3(G * S), 256, 0, stream>>>(h2, batch, part, Nn, DOUT, S);
  pool_reduce<<<dim3((G * DOUT + 255) / 256), 256, 0, stream>>>(part, batch, out, Nn, DOUT, S, G);
}